// Round 2
// baseline (2534.762 us; speedup 1.0000x reference)
//
#include <hip/hip_runtime.h>

#define D 128
#define K 64
#define NROWS 200000
#define BATCH 32
#define TPB 256
#define MU_STRIDE 132          // pad 128 -> 132 floats: float4 reads conflict-free
#define PSLOT (K * D + K)     // 8256 floats per block partial slot

__device__ __forceinline__ float dot4(const float4 a, const float4 b) {
  return a.x * b.x + a.y * b.y + a.z * b.z + a.w * b.w;
}

// Fused per-iteration pass: dist = normalize(X) @ normalize(mu)^T, softmax,
// partial cluster_mean / cluster_r accumulation. One read of X per iteration.
__global__ __launch_bounds__(TPB, 2) void pass_kernel(
    const float* __restrict__ data,
    const float* __restrict__ mu_raw,
    const int* __restrict__ temp_p,
    float* __restrict__ partials,
    float* __restrict__ r_out,
    const int write_r, const int nblk)
{
  __shared__ float lds_mu[K * MU_STRIDE];   // 33792 B, normalized mu
  __shared__ float lds_x[BATCH * D];        // 16384 B, raw rows
  __shared__ float lds_inv[BATCH];          // 1/(||x||+eps)
  __shared__ float lds_r[BATCH * K];        // 8192 B, softmax r
  __shared__ float lds_rs[4 * K];           // per-wave cluster_r partials

  const int t = threadIdx.x;
  const int wave = t >> 6;
  const int lane = t & 63;
  const float temp = (float)(*temp_p);

  // ---- stage + normalize mu: 4 threads per row, 32 floats each ----
  {
    const int row = t >> 2;
    const int ch = t & 3;
    const float4* src = (const float4*)(mu_raw + row * D + ch * 32);
    float4 v[8];
    float ss = 0.f;
#pragma unroll
    for (int i = 0; i < 8; ++i) { v[i] = src[i]; ss += dot4(v[i], v[i]); }
    ss += __shfl_xor(ss, 1);
    ss += __shfl_xor(ss, 2);
    const float inv = 1.f / (sqrtf(ss) + 1e-6f);
    float4* dst = (float4*)(lds_mu + row * MU_STRIDE + ch * 32);
#pragma unroll
    for (int i = 0; i < 8; ++i)
      dst[i] = make_float4(v[i].x * inv, v[i].y * inv, v[i].z * inv, v[i].w * inv);
  }

  float accm[32];
#pragma unroll
  for (int i = 0; i < 32; ++i) accm[i] = 0.f;
  float rsum = 0.f;

  __syncthreads();

  for (int batch = blockIdx.x; batch < NROWS / BATCH; batch += nblk) {
    const int row0 = batch * BATCH;

    // ---- stage 32 raw rows; compute row inv-norms from registers ----
    {
      const float4* src = (const float4*)(data + (size_t)row0 * D) + t * 4;
      float4 v0 = src[0], v1 = src[1], v2 = src[2], v3 = src[3];
      float ss = dot4(v0, v0) + dot4(v1, v1) + dot4(v2, v2) + dot4(v3, v3);
      ss += __shfl_xor(ss, 1);   // 8 threads (16 floats each) per row
      ss += __shfl_xor(ss, 2);
      ss += __shfl_xor(ss, 4);
      float4* dst = (float4*)lds_x + t * 4;
      dst[0] = v0; dst[1] = v1; dst[2] = v2; dst[3] = v3;
      if ((t & 7) == 0) lds_inv[t >> 3] = 1.f / (sqrtf(ss) + 1e-6f);
    }
    __syncthreads();

    // ---- dist: wave handles 8 rows, lane = cluster (K == 64) ----
    float a[8];
#pragma unroll
    for (int r = 0; r < 8; ++r) a[r] = 0.f;
    {
      const float* mup = lds_mu + lane * MU_STRIDE;
      const float* xp = lds_x + (wave * 8) * D;
#pragma unroll 2
      for (int d4 = 0; d4 < 32; ++d4) {
        const float4 m = *(const float4*)(mup + 4 * d4);
#pragma unroll
        for (int r = 0; r < 8; ++r) {
          const float4 xv = *(const float4*)(xp + r * D + 4 * d4);  // broadcast
          a[r] += dot4(m, xv);
        }
      }
    }

    // ---- softmax across lanes; |logit| <= 30 so no max-subtraction needed ----
#pragma unroll
    for (int r = 0; r < 8; ++r) {
      const int row = wave * 8 + r;
      const float e = __expf(temp * a[r] * lds_inv[row]);
      float s = e;
      s += __shfl_xor(s, 1);  s += __shfl_xor(s, 2);  s += __shfl_xor(s, 4);
      s += __shfl_xor(s, 8);  s += __shfl_xor(s, 16); s += __shfl_xor(s, 32);
      const float rv = e / s;
      rsum += rv;
      lds_r[row * K + lane] = rv;
      if (write_r) r_out[(size_t)(row0 + row) * K + lane] = rv;
    }
    __syncthreads();

    // ---- accumulate cluster_mean: wave owns dims [wave*32, wave*32+32) ----
#pragma unroll 2
    for (int row = 0; row < BATCH; ++row) {
      const float w8 = lds_r[row * K + lane] * lds_inv[row];
      const float4* xr = (const float4*)(lds_x + row * D + wave * 32);
#pragma unroll
      for (int j = 0; j < 8; ++j) {
        const float4 xv = xr[j];   // broadcast
        accm[4 * j + 0] += w8 * xv.x;
        accm[4 * j + 1] += w8 * xv.y;
        accm[4 * j + 2] += w8 * xv.z;
        accm[4 * j + 3] += w8 * xv.w;
      }
    }
    __syncthreads();
  }

  // ---- per-block partial out ----
  float* pm = partials + (size_t)blockIdx.x * PSLOT;
  float4* pd = (float4*)(pm + lane * D + wave * 32);
#pragma unroll
  for (int j = 0; j < 8; ++j)
    pd[j] = make_float4(accm[4 * j], accm[4 * j + 1], accm[4 * j + 2], accm[4 * j + 3]);
  lds_rs[wave * K + lane] = rsum;
  __syncthreads();
  if (wave == 0)
    pm[K * D + lane] =
        lds_rs[lane] + lds_rs[K + lane] + lds_rs[2 * K + lane] + lds_rs[3 * K + lane];
}

// Sum per-block partials, mu = cluster_mean / cluster_r. Deterministic.
__global__ __launch_bounds__(128) void reduce_update_kernel(
    const float* __restrict__ partials, float* __restrict__ mu_raw,
    float* __restrict__ mu_out, const int write_mu, const int nblk)
{
  const int c = blockIdx.x;    // 64 blocks = clusters
  const int d = threadIdx.x;   // 128 threads = dims
  float s0 = 0.f, s1 = 0.f, s2 = 0.f, s3 = 0.f;
  int b = 0;
  for (; b + 4 <= nblk; b += 4) {
    s0 += partials[(size_t)(b + 0) * PSLOT + c * D + d];
    s1 += partials[(size_t)(b + 1) * PSLOT + c * D + d];
    s2 += partials[(size_t)(b + 2) * PSLOT + c * D + d];
    s3 += partials[(size_t)(b + 3) * PSLOT + c * D + d];
  }
  for (; b < nblk; ++b) s0 += partials[(size_t)b * PSLOT + c * D + d];
  const float s = (s0 + s1) + (s2 + s3);

  float rs = 0.f;
  for (int bb = (d & 63); bb < nblk; bb += 64)
    rs += partials[(size_t)bb * PSLOT + K * D + c];
  rs += __shfl_xor(rs, 1);  rs += __shfl_xor(rs, 2);  rs += __shfl_xor(rs, 4);
  rs += __shfl_xor(rs, 8);  rs += __shfl_xor(rs, 16); rs += __shfl_xor(rs, 32);

  const float v = s / rs;
  mu_raw[c * D + d] = v;
  if (write_mu) mu_out[c * D + d] = v;
}

extern "C" void kernel_launch(void* const* d_in, const int* in_sizes, int n_in,
                              void* d_out, int out_size, void* d_ws, size_t ws_size,
                              hipStream_t stream)
{
  const float* data = (const float*)d_in[0];   // [200000, 128] f32
  const float* init = (const float*)d_in[1];   // [64, 128] f32
  const int* temp_p = (const int*)d_in[2];     // scalar 30
  float* out = (float*)d_out;                  // [0,8192) mu, [8192,...) r

  int nblk = 512;
  const size_t need = ((size_t)nblk * PSLOT + (size_t)K * D) * sizeof(float);
  if (ws_size < need) {
    nblk = (int)((ws_size / sizeof(float) - (size_t)K * D) / PSLOT);
    if (nblk < 1) nblk = 1;
  }
  float* partials = (float*)d_ws;
  float* mu_raw = partials + (size_t)nblk * PSLOT;

  // 10 iterations of _cluster#1 + 1 iteration of _cluster#2 == 11 identical steps;
  // r output comes from iteration 11's dist, mu output from iteration 11's update.
  for (int it = 0; it < 11; ++it) {
    const float* mu_src = (it == 0) ? init : mu_raw;
    const int last = (it == 10) ? 1 : 0;
    pass_kernel<<<dim3(nblk), dim3(TPB), 0, stream>>>(
        data, mu_src, temp_p, partials, out + K * D, last, nblk);
    reduce_update_kernel<<<dim3(K), dim3(D), 0, stream>>>(
        partials, mu_raw, out, last, nblk);
  }
}

// Round 3
// 602.666 us; speedup vs baseline: 4.2059x; 4.2059x over previous
//
#include <hip/hip_runtime.h>

#define D 128
#define K 64
#define NROWS 200000
#define RT_ROWS 64
#define NTILES (NROWS / RT_ROWS)   // 3125
#define TPB 256
#define PSLOT (K * D + K)          // 8256 floats per block partial slot
#define NBLK_MAX 512

typedef __attribute__((ext_vector_type(8))) short bf16x8;   // 8 bf16 = 4 VGPR
typedef __attribute__((ext_vector_type(4))) float f32x4;

// LDS byte offsets (single arena, 58368 B -> 2 blocks/CU)
#define XH 0          // x_hi  [64][128] bf16, row stride 256B, swizzled
#define XL 16384      // x_lo  same
#define ML 32768      // mu_lo same (mu_hi lives in registers)
#define RTT 49152     // r_t   [64 clusters][64 rows] bf16, stride 128B, swizzled
#define RSRED 57344   // [4][64] f32 cluster_r wave partials
#define LDS_BYTES 58368

__device__ __forceinline__ int xrow_off(int row, int dim) {
  return (row * 256 + dim * 2) ^ ((row & 7) << 4);   // T2-style XOR swizzle
}
__device__ __forceinline__ int rt_off(int c, int row) {
  return (c * 128 + row * 2) ^ ((c & 7) << 4);
}
__device__ __forceinline__ ushort f2bf(float x) {     // round-to-nearest-even
  uint u = __float_as_uint(x);
  return (ushort)((u + 0x7FFF + ((u >> 16) & 1)) >> 16);
}
__device__ __forceinline__ float bf2f(ushort b) {
  return __uint_as_float(((uint)b) << 16);
}

// normalize one row-chunk (32 floats of a row, 4 threads/row) and store
// bf16 hi/lo split into swizzled LDS.
__device__ __forceinline__ void norm_split_store(const float4* xv, char* smem,
                                                 int off_hi, int off_lo,
                                                 int row, int d0) {
  float ss = 0.f;
#pragma unroll
  for (int i = 0; i < 8; ++i)
    ss += xv[i].x * xv[i].x + xv[i].y * xv[i].y + xv[i].z * xv[i].z + xv[i].w * xv[i].w;
  ss += __shfl_xor(ss, 1);
  ss += __shfl_xor(ss, 2);
  const float inv = 1.f / (sqrtf(ss) + 1e-6f);
#pragma unroll
  for (int jb = 0; jb < 4; ++jb) {
    float f[8] = { xv[2*jb].x, xv[2*jb].y, xv[2*jb].z, xv[2*jb].w,
                   xv[2*jb+1].x, xv[2*jb+1].y, xv[2*jb+1].z, xv[2*jb+1].w };
    uint hp[4], lp[4];
#pragma unroll
    for (int q = 0; q < 4; ++q) {
      float a0 = f[2*q] * inv, a1 = f[2*q+1] * inv;
      ushort h0 = f2bf(a0), h1 = f2bf(a1);
      ushort g0 = f2bf(a0 - bf2f(h0)), g1 = f2bf(a1 - bf2f(h1));
      hp[q] = (uint)h0 | ((uint)h1 << 16);
      lp[q] = (uint)g0 | ((uint)g1 << 16);
    }
    *(uint4*)(smem + off_hi + xrow_off(row, d0 + 8*jb)) = make_uint4(hp[0], hp[1], hp[2], hp[3]);
    *(uint4*)(smem + off_lo + xrow_off(row, d0 + 8*jb)) = make_uint4(lp[0], lp[1], lp[2], lp[3]);
  }
}

__global__ __launch_bounds__(TPB, 2) void pass_kernel(
    const float* __restrict__ data, const float* __restrict__ mu_src,
    const int* __restrict__ temp_p, float* __restrict__ partials,
    float* __restrict__ r_out, const int write_r, const int nblk)
{
  __shared__ __align__(16) char smem[LDS_BYTES];
  const int t = threadIdx.x;
  const int w = t >> 6;         // wave id (dist: rows 16w..; acc: dims 32w..)
  const int l = t & 63;
  const int lg = l >> 4;        // lane group
  const int lr = l & 15;
  const float temp = (float)(*temp_p);
  const int row_t = t >> 2, d0s = (t & 3) * 32;   // staging map: 4 thr/row

  // ---------- prologue: stage normalized mu (hi->XH scratch, lo->ML) ----------
  {
    float4 mv[8];
    const float4* src = (const float4*)(mu_src + row_t * D + d0s);
#pragma unroll
    for (int i = 0; i < 8; ++i) mv[i] = src[i];
    norm_split_store(mv, smem, XH, ML, row_t, d0s);
  }
  __syncthreads();
  // hoist mu_hi B-fragments to registers: B[k=kc*32+lg*8+j][n=16ns+lr]=mu[n][k]
  bf16x8 muh[4][4];
#pragma unroll
  for (int kc = 0; kc < 4; ++kc)
#pragma unroll
    for (int ns = 0; ns < 4; ++ns)
      muh[kc][ns] = *(const bf16x8*)(smem + XH + xrow_off(16*ns + lr, kc*32 + lg*8));
  __syncthreads();   // XH free for x tiles now

  f32x4 accm[4][2];   // [msub(cluster/16)][n2(dim16 within wave's 32-dim strip)]
#pragma unroll
  for (int ms = 0; ms < 4; ++ms)
#pragma unroll
    for (int n2 = 0; n2 < 2; ++n2) accm[ms][n2] = (f32x4){0.f, 0.f, 0.f, 0.f};
  float rsum[4] = {0.f, 0.f, 0.f, 0.f};

  int tile = blockIdx.x;
  float4 xr[8];
  if (tile < NTILES) {
    const float4* s = (const float4*)(data + (size_t)(tile * RT_ROWS + row_t) * D + d0s);
#pragma unroll
    for (int i = 0; i < 8; ++i) xr[i] = s[i];
  }

  for (; tile < NTILES; tile += nblk) {
    // ---- stage x: normalize + bf16 hi/lo split into swizzled LDS ----
    norm_split_store(xr, smem, XH, XL, row_t, d0s);
    __syncthreads();
    // ---- prefetch next tile (hides HBM latency under compute) ----
    const int nxt = tile + nblk;
    if (nxt < NTILES) {
      const float4* s = (const float4*)(data + (size_t)(nxt * RT_ROWS + row_t) * D + d0s);
#pragma unroll
      for (int i = 0; i < 8; ++i) xr[i] = s[i];
    }

    // ---- dist: D[row][cluster], wave w owns rows 16w..16w+15, all 64 clusters
    f32x4 pacc[4];
#pragma unroll
    for (int ns = 0; ns < 4; ++ns) pacc[ns] = (f32x4){0.f, 0.f, 0.f, 0.f};
#pragma unroll
    for (int kc = 0; kc < 4; ++kc) {
      const int doff = kc * 32 + lg * 8;
      bf16x8 ah = *(const bf16x8*)(smem + XH + xrow_off(16*w + lr, doff));
      bf16x8 al = *(const bf16x8*)(smem + XL + xrow_off(16*w + lr, doff));
#pragma unroll
      for (int ns = 0; ns < 4; ++ns) {
        bf16x8 bl = *(const bf16x8*)(smem + ML + xrow_off(16*ns + lr, doff));
        pacc[ns] = __builtin_amdgcn_mfma_f32_16x16x32_bf16(ah, muh[kc][ns], pacc[ns], 0, 0, 0);
        pacc[ns] = __builtin_amdgcn_mfma_f32_16x16x32_bf16(al, muh[kc][ns], pacc[ns], 0, 0, 0);
        pacc[ns] = __builtin_amdgcn_mfma_f32_16x16x32_bf16(ah, bl, pacc[ns], 0, 0, 0);
      }
    }

    // ---- softmax over clusters (row = 16w + lg*4 + j; cluster = 16ns + lr)
    float rv[4][4], sinv[4];
#pragma unroll
    for (int j = 0; j < 4; ++j) {
      float sj = 0.f;
#pragma unroll
      for (int ns = 0; ns < 4; ++ns) { rv[ns][j] = __expf(temp * pacc[ns][j]); sj += rv[ns][j]; }
      sj += __shfl_xor(sj, 1); sj += __shfl_xor(sj, 2);
      sj += __shfl_xor(sj, 4); sj += __shfl_xor(sj, 8);
      sinv[j] = 1.f / sj;
    }
#pragma unroll
    for (int ns = 0; ns < 4; ++ns) {
      float r0 = rv[ns][0]*sinv[0], r1 = rv[ns][1]*sinv[1],
            r2 = rv[ns][2]*sinv[2], r3 = rv[ns][3]*sinv[3];
      ushort h0 = f2bf(r0), h1 = f2bf(r1), h2 = f2bf(r2), h3 = f2bf(r3);
      // cluster_r from the same rounded values used for cluster_mean
      rsum[ns] += (bf2f(h0) + bf2f(h1)) + (bf2f(h2) + bf2f(h3));
      uint p0 = (uint)h0 | ((uint)h1 << 16);
      uint p1 = (uint)h2 | ((uint)h3 << 16);
      *(uint2*)(smem + RTT + rt_off(16*ns + lr, 16*w + lg*4)) = make_uint2(p0, p1);
      if (write_r) {
        const size_t rb = (size_t)tile * RT_ROWS + 16*w + lg*4;
        r_out[(rb + 0) * K + 16*ns + lr] = r0;
        r_out[(rb + 1) * K + 16*ns + lr] = r1;
        r_out[(rb + 2) * K + 16*ns + lr] = r2;
        r_out[(rb + 3) * K + 16*ns + lr] = r3;
      }
    }
    __syncthreads();

    // ---- accumulate: C_mean[cluster][dim] += r^T @ Xn, wave w dims 32w..32w+31
#pragma unroll
    for (int kc2 = 0; kc2 < 2; ++kc2) {
      const int k0 = kc2 * 32 + lg * 8;
      bf16x8 af[4];
#pragma unroll
      for (int ms = 0; ms < 4; ++ms)
        af[ms] = *(const bf16x8*)(smem + RTT + rt_off(16*ms + lr, k0));
#pragma unroll
      for (int n2 = 0; n2 < 2; ++n2) {
        const int dim = 32*w + 16*n2 + lr;
        bf16x8 bfv;
#pragma unroll
        for (int j = 0; j < 8; ++j)
          bfv[j] = *(const short*)(smem + XH + xrow_off(k0 + j, dim));
#pragma unroll
        for (int ms = 0; ms < 4; ++ms)
          accm[ms][n2] = __builtin_amdgcn_mfma_f32_16x16x32_bf16(af[ms], bfv, accm[ms][n2], 0, 0, 0);
      }
    }
    __syncthreads();
  }

  // ---- epilogue: per-block partials ----
  float* pm = partials + (size_t)blockIdx.x * PSLOT;
#pragma unroll
  for (int ms = 0; ms < 4; ++ms)
#pragma unroll
    for (int n2 = 0; n2 < 2; ++n2)
#pragma unroll
      for (int j = 0; j < 4; ++j)
        pm[(16*ms + lg*4 + j) * D + 32*w + 16*n2 + lr] = accm[ms][n2][j];
#pragma unroll
  for (int ns = 0; ns < 4; ++ns) {
    rsum[ns] += __shfl_xor(rsum[ns], 16);
    rsum[ns] += __shfl_xor(rsum[ns], 32);
  }
  float* rs = (float*)(smem + RSRED);
  if (lg == 0)
#pragma unroll
    for (int ns = 0; ns < 4; ++ns) rs[w * K + 16*ns + lr] = rsum[ns];
  __syncthreads();
  if (t < K) pm[K*D + t] = (rs[t] + rs[K + t]) + (rs[2*K + t] + rs[3*K + t]);
}

// grid 256: block b -> cluster c = b>>2, dim quarter dq = (b&3)*32
__global__ __launch_bounds__(1024) void reduce_update_kernel(
    const float* __restrict__ partials, float* __restrict__ mu_raw,
    float* __restrict__ mu_out, const int write_mu, const int nblk)
{
  __shared__ float red[1024];
  const int c = blockIdx.x >> 2, dq = (blockIdx.x & 3) * 32;
  const int t = threadIdx.x;

  // cluster_r[c]
  float rp = 0.f;
  for (int b = t; b < nblk; b += 1024) rp += partials[(size_t)b * PSLOT + K*D + c];
  red[t] = rp; __syncthreads();
  if (t < 512) red[t] += red[t + 512];
  __syncthreads();
  if (t < 256) red[t] += red[t + 256];
  __syncthreads();
  if (t < 128) red[t] += red[t + 128];
  __syncthreads();
  if (t < 64) {
    float x = red[t] + red[t + 64];
    x += __shfl_xor(x, 1);  x += __shfl_xor(x, 2);  x += __shfl_xor(x, 4);
    x += __shfl_xor(x, 8);  x += __shfl_xor(x, 16); x += __shfl_xor(x, 32);
    if (t == 0) red[0] = x;
  }
  __syncthreads();
  const float rs_total = red[0];
  __syncthreads();

  // cluster_mean[c][dq..dq+31]
  const int dl = t & 31, h = t >> 5;   // 32 b-groups
  float s = 0.f;
  for (int b = h; b < nblk; b += 32) s += partials[(size_t)b * PSLOT + c*D + dq + dl];
  red[t] = s; __syncthreads();
  if (t < 512) red[t] += red[t + 512];
  __syncthreads();
  if (t < 256) red[t] += red[t + 256];
  __syncthreads();
  if (t < 128) red[t] += red[t + 128];
  __syncthreads();
  if (t < 64) red[t] += red[t + 64];
  __syncthreads();
  if (t < 32) {
    const float v = (red[t] + red[t + 32]) / rs_total;
    mu_raw[c*D + dq + t] = v;
    if (write_mu) mu_out[c*D + dq + t] = v;
  }
}

extern "C" void kernel_launch(void* const* d_in, const int* in_sizes, int n_in,
                              void* d_out, int out_size, void* d_ws, size_t ws_size,
                              hipStream_t stream)
{
  const float* data = (const float*)d_in[0];   // [200000,128] f32
  const float* init = (const float*)d_in[1];   // [64,128] f32
  const int* temp_p = (const int*)d_in[2];     // scalar 30
  float* out = (float*)d_out;                  // [0,8192) mu, then r

  int nblk = NBLK_MAX;
  const size_t need = ((size_t)nblk * PSLOT + (size_t)K * D) * sizeof(float);
  if (ws_size < need) {
    nblk = (int)((ws_size / sizeof(float) - (size_t)K * D) / PSLOT);
    if (nblk < 1) nblk = 1;
  }
  float* partials = (float*)d_ws;
  float* mu_raw = partials + (size_t)nblk * PSLOT;

  // 10 iterations of _cluster#1 + 1 of _cluster#2 == 11 identical steps.
  for (int it = 0; it < 11; ++it) {
    const float* mu_src = (it == 0) ? init : mu_raw;
    const int last = (it == 10) ? 1 : 0;
    pass_kernel<<<dim3(nblk), dim3(TPB), 0, stream>>>(
        data, mu_src, temp_p, partials, out + K*D, last, nblk);
    reduce_update_kernel<<<dim3(256), dim3(1024), 0, stream>>>(
        partials, mu_raw, out, last, nblk);
  }
}